// Round 1
// baseline (617.936 us; speedup 1.0000x reference)
//
#include <hip/hip_runtime.h>

// ---------- model dims ----------
#define NB   32
#define TT   46
#define RNN  128
#define CDIM 24
#define GD   256
#define GIN  180

typedef __attribute__((ext_vector_type(8))) short  bf16x8;
typedef __attribute__((ext_vector_type(4))) short  s16x4;
typedef __attribute__((ext_vector_type(8))) unsigned short u16x8;
typedef __attribute__((ext_vector_type(4))) float  f32x4;

__device__ __forceinline__ unsigned short f2bf(float v) {
    unsigned u = __float_as_uint(v);
    u = u + 0x7fffu + ((u >> 16) & 1u);   // RNE
    return (unsigned short)(u >> 16);
}

// ---------------- LSTM (incl. embedding lookup) ----------------
// one block per batch item; 512 threads = one gate-unit each; weights in VGPRs
__global__ __launch_bounds__(512) void lstm_kernel(
    const int* __restrict__ q, const float* __restrict__ embW,
    const float* __restrict__ Wih, const float* __restrict__ Whh,
    const float* __restrict__ bih, const float* __restrict__ bhh,
    float* __restrict__ qf)
{
    const int n = blockIdx.x, tid = threadIdx.x;
    __shared__ float xs[32], hs[RNN], cs[RNN], zg[512];
    float wih[32], whh[RNN];
#pragma unroll
    for (int j = 0; j < 32; j++) wih[j] = Wih[tid * 32 + j];
#pragma unroll
    for (int j = 0; j < RNN; j++) whh[j] = Whh[tid * RNN + j];
    const float bias = bih[tid] + bhh[tid];
    if (tid < RNN) { hs[tid] = 0.f; cs[tid] = 0.f; }
    __syncthreads();
    for (int t = 0; t < TT; t++) {
        if (tid < 32) xs[tid] = embW[q[n * TT + t] * 32 + tid];
        __syncthreads();
        float acc = bias;
#pragma unroll
        for (int j = 0; j < 32; j++) acc += wih[j] * xs[j];
#pragma unroll
        for (int j = 0; j < RNN; j++) acc += whh[j] * hs[j];
        zg[tid] = acc;
        __syncthreads();
        if (tid < RNN) {
            float ig = 1.f / (1.f + expf(-zg[tid]));
            float fg = 1.f / (1.f + expf(-zg[RNN + tid]));
            float gg = tanhf(zg[2 * RNN + tid]);
            float og = 1.f / (1.f + expf(-zg[3 * RNN + tid]));
            float cn = fg * cs[tid] + ig * gg;
            cs[tid] = cn;
            hs[tid] = og * tanhf(cn);
        }
        __syncthreads();
    }
    if (tid < RNN) qf[n * RNN + tid] = hs[tid];
}

// ---------------- conv 3x3 s2 p1 + bias, fused BN-stat partials ----------------
template<int CIN, int BS>
__global__ __launch_bounds__(BS) void conv_s2(
    const float* __restrict__ in, const float* __restrict__ W,
    const float* __restrict__ bias, float* __restrict__ out,
    float* __restrict__ stats,
    int COUT, int HIN, int WIN, int HOUT, int WOUT)
{
    const int hw  = HOUT * WOUT;
    const int bpi = (hw + BS - 1) / BS;
    const int nco = blockIdx.x / bpi;
    const int pos = (blockIdx.x % bpi) * BS + threadIdx.x;
    const int co  = nco % COUT;
    const int n   = nco / COUT;
    float v = 0.f;
    if (pos < hw) {
        const int oy = pos / WOUT, ox = pos % WOUT;
        float acc = bias[co];
        const float* wbase = W + co * CIN * 9;
        for (int ci = 0; ci < CIN; ci++) {
            const float* ip = in + (size_t)(n * CIN + ci) * HIN * WIN;
            const float* wp = wbase + ci * 9;
#pragma unroll
            for (int ky = 0; ky < 3; ky++) {
                int iy = oy * 2 - 1 + ky;
                if ((unsigned)iy < (unsigned)HIN) {
                    const float* row = ip + iy * WIN;
#pragma unroll
                    for (int kx = 0; kx < 3; kx++) {
                        int ix = ox * 2 - 1 + kx;
                        if ((unsigned)ix < (unsigned)WIN) acc += row[ix] * wp[ky * 3 + kx];
                    }
                }
            }
        }
        out[(size_t)nco * hw + pos] = acc;
        v = acc;
    }
    // block reduce (single co per block by construction)
    float s1 = v, s2 = v * v;
#pragma unroll
    for (int off = 32; off > 0; off >>= 1) {
        s1 += __shfl_down(s1, off, 64);
        s2 += __shfl_down(s2, off, 64);
    }
    __shared__ float r1[BS / 64], r2[BS / 64];
    const int wv = threadIdx.x >> 6;
    if ((threadIdx.x & 63) == 0) { r1[wv] = s1; r2[wv] = s2; }
    __syncthreads();
    if (threadIdx.x == 0) {
        float t1 = 0.f, t2 = 0.f;
#pragma unroll
        for (int u = 0; u < BS / 64; u++) { t1 += r1[u]; t2 += r2[u]; }
        atomicAdd(&stats[co * 2],     t1);
        atomicAdd(&stats[co * 2 + 1], t2);
    }
}

// ---------------- BN (batch stats) + ReLU, in place ----------------
__global__ __launch_bounds__(256) void bn_relu(
    float* __restrict__ x, const float* __restrict__ stats,
    const float* __restrict__ g, const float* __restrict__ b,
    int COUT, int HW_, int total, float invM)
{
    int idx = blockIdx.x * 256 + threadIdx.x;
    if (idx >= total) return;
    int co = (idx / HW_) % COUT;
    float mu  = stats[co * 2] * invM;
    float var = stats[co * 2 + 1] * invM - mu * mu;
    float rs  = rsqrtf(var + 1e-5f);
    float v = x[idx];
    v = (v - mu) * rs * g[co] + b[co];
    x[idx] = v > 0.f ? v : 0.f;
}

// ---------------- fp32 -> bf16 convert ----------------
__global__ __launch_bounds__(256) void cvt_bf16(
    const float* __restrict__ src, unsigned short* __restrict__ dst, int n)
{
    int i = blockIdx.x * 256 + threadIdx.x;
    if (i < n) dst[i] = f2bf(src[i]);
}

// ---------------- per-object projections A,B and question term QT ----------------
// A[n,i,k] = W0[k,0:26].obj ; B[n,i,k] = W0[k,26:52].obj ; QT[n,k] = W0[k,52:180].q + b0[k]
__global__ __launch_bounds__(256) void abqt_kernel(
    const float* __restrict__ feat,  // (32,24,8,8)
    const float* __restrict__ qf,    // (32,128)
    const float* __restrict__ g0W,   // (256,180)
    const float* __restrict__ g0b,
    float* __restrict__ A, float* __restrict__ Bm, float* __restrict__ QT)
{
    const int n = blockIdx.x >> 6;
    const int i = blockIdx.x & 63;
    const int k = threadIdx.x;
    __shared__ float obj[26];
    __shared__ float qs[RNN];
    if (k < 24)       obj[k]  = feat[((n * CDIM + k) * 8 + (i >> 3)) * 8 + (i & 7)];
    else if (k == 24) obj[24] = (float)(i & 7)  * (1.f / 7.f);   // xc
    else if (k == 25) obj[25] = (float)(i >> 3) * (1.f / 7.f);   // yc
    if (k >= 128) qs[k - 128] = qf[n * RNN + (k - 128)];
    __syncthreads();
    const float* wr = g0W + k * GIN;
    float a = 0.f, bb = 0.f;
#pragma unroll
    for (int c = 0; c < 26; c++) { a += wr[c] * obj[c]; bb += wr[26 + c] * obj[c]; }
    A [(blockIdx.x << 8) + k] = a;
    Bm[(blockIdx.x << 8) + k] = bb;
    if (i == 0) {
        float qv = g0b[k];
#pragma unroll
        for (int d = 0; d < RNN; d++) qv += wr[52 + d] * qs[d];
        QT[(n << 8) + k] = qv;
    }
}

// ---------------- fused 3x(256->256) g-MLP + pair sum, bf16 MFMA ----------------
// block = (n,i): 64 pair-rows; X in LDS (bf16, XOR-swizzled); acc in regs over full K
__global__ __launch_bounds__(256) void gs_fused(
    const float* __restrict__ A, const float* __restrict__ Bm, const float* __restrict__ QT,
    const unsigned short* __restrict__ Wb,   // (3,256,256) bf16
    const float* __restrict__ gsb,           // (3,256)
    float* __restrict__ partial)             // (2048,256)
{
    __shared__ __align__(16) unsigned short Xs[64 * 256];   // 32 KB
    __shared__ __align__(16) unsigned short Wls[256 * 32];  // 16 KB
    __shared__ float AQ[256];
    __shared__ float biasv[3][256];
    const int bb = blockIdx.x, n = bb >> 6, tid = threadIdx.x;
    const int lane = tid & 63, w = tid >> 6, l15 = lane & 15, lh = lane >> 4;

    AQ[tid] = A[(bb << 8) + tid] + QT[(n << 8) + tid];
#pragma unroll
    for (int l = 0; l < 3; l++) biasv[l][tid] = gsb[(l << 8) + tid];
    __syncthreads();

    // build h0 = relu(A_i + B_j + QT) into Xs; task = (row j, 8-col group g)
#pragma unroll
    for (int it = 0; it < 8; it++) {
        int task = tid + (it << 8);
        int j = task >> 5, g = task & 31;
        const f32x4* bp = (const f32x4*)(Bm + (((n << 6) + j) << 8) + (g << 3));
        f32x4 b0 = bp[0], b1 = bp[1];
        u16x8 pk;
        int c0 = g << 3;
#pragma unroll
        for (int p = 0; p < 4; p++) {
            pk[p]     = f2bf(fmaxf(b0[p] + AQ[c0 + p], 0.f));
            pk[p + 4] = f2bf(fmaxf(b1[p] + AQ[c0 + 4 + p], 0.f));
        }
        *(u16x8*)((char*)Xs + j * 512 + ((g ^ (j & 7)) << 4)) = pk;
    }

    f32x4 acc[4][4];                 // [col-tile][row-slab]
    const f32x4 zero4 = {0.f, 0.f, 0.f, 0.f};
    for (int layer = 0; layer < 3; layer++) {
#pragma unroll
        for (int tc = 0; tc < 4; tc++)
#pragma unroll
            for (int sl = 0; sl < 4; sl++) acc[tc][sl] = zero4;
        const unsigned short* Wl = Wb + (layer << 16);
        for (int kb = 0; kb < 8; kb++) {
            __syncthreads();
            {   // stage W[256][kb*32..+32] to LDS (swizzled)
                const f32x4* src = (const f32x4*)(Wl + (tid << 8) + (kb << 5));
                char* drow = (char*)Wls + (tid << 6);
                int sw = (tid >> 1) & 3;
#pragma unroll
                for (int u = 0; u < 4; u++) *(f32x4*)(drow + ((u ^ sw) << 4)) = src[u];
            }
            __syncthreads();
            bf16x8 wf[4], xf[4];
#pragma unroll
            for (int tc = 0; tc < 4; tc++) {
                int ko = (w << 6) + (tc << 4) + l15;
                int bu = lh ^ ((ko >> 1) & 3);
                wf[tc] = *(const bf16x8*)((const char*)Wls + (ko << 6) + (bu << 4));
            }
#pragma unroll
            for (int sl = 0; sl < 4; sl++) {
                int ar = (sl << 4) + l15;
                int au = ((kb << 2) + lh) ^ (ar & 7);
                xf[sl] = *(const bf16x8*)((const char*)Xs + ar * 512 + (au << 4));
            }
#pragma unroll
            for (int tc = 0; tc < 4; tc++)
#pragma unroll
                for (int sl = 0; sl < 4; sl++)
                    acc[tc][sl] = __builtin_amdgcn_mfma_f32_16x16x32_bf16(
                        wf[tc], xf[sl], acc[tc][sl], 0, 0, 0);
        }
        if (layer < 2) {
            __syncthreads();  // all waves done reading Xs before overwrite
#pragma unroll
            for (int tc = 0; tc < 4; tc++) {
                int c0 = (w << 6) + (tc << 4) + (lh << 2);
                float b0 = biasv[layer][c0],     b1 = biasv[layer][c0 + 1];
                float b2 = biasv[layer][c0 + 2], b3 = biasv[layer][c0 + 3];
#pragma unroll
                for (int sl = 0; sl < 4; sl++) {
                    int row = (sl << 4) + l15;
                    s16x4 pk;
                    pk[0] = (short)f2bf(fmaxf(acc[tc][sl][0] + b0, 0.f));
                    pk[1] = (short)f2bf(fmaxf(acc[tc][sl][1] + b1, 0.f));
                    pk[2] = (short)f2bf(fmaxf(acc[tc][sl][2] + b2, 0.f));
                    pk[3] = (short)f2bf(fmaxf(acc[tc][sl][3] + b3, 0.f));
                    *(s16x4*)((char*)Xs + row * 512 + (((c0 >> 3) ^ (row & 7)) << 4)
                              + ((c0 & 7) << 1)) = pk;
                }
            }
        } else {
            // final: relu + sum over the block's 64 pair-rows -> partial[bb][col]
#pragma unroll
            for (int tc = 0; tc < 4; tc++) {
                int c0 = (w << 6) + (tc << 4) + (lh << 2);
                f32x4 cs;
#pragma unroll
                for (int p = 0; p < 4; p++) {
                    float bv = biasv[2][c0 + p];
                    float s = 0.f;
#pragma unroll
                    for (int sl = 0; sl < 4; sl++) s += fmaxf(acc[tc][sl][p] + bv, 0.f);
                    s += __shfl_xor(s, 1, 64);
                    s += __shfl_xor(s, 2, 64);
                    s += __shfl_xor(s, 4, 64);
                    s += __shfl_xor(s, 8, 64);
                    cs[p] = s;
                }
                if (l15 == 0) *(f32x4*)(partial + (size_t)bb * 256 + c0) = cs;
            }
        }
    }
}

// ---------------- f-MLP: sum partials -> f0 relu -> f1 relu -> f2 ----------------
__global__ __launch_bounds__(256) void f_mlp(
    const float* __restrict__ partial,
    const float* __restrict__ f0W, const float* __restrict__ f0b,
    const float* __restrict__ f1W, const float* __restrict__ f1b,
    const float* __restrict__ f2W, const float* __restrict__ f2b,
    float* __restrict__ out)
{
    const int n = blockIdx.x, k = threadIdx.x;
    __shared__ float fin[256], h1[256], h2[256];
    float s = 0.f;
    for (int b = 0; b < 64; b++) s += partial[(size_t)(n * 64 + b) * 256 + k];
    fin[k] = s;
    __syncthreads();
    const float* wr = f0W + k * 256;
    float a = f0b[k];
    for (int c = 0; c < 256; c++) a += wr[c] * fin[c];
    h1[k] = fmaxf(a, 0.f);
    __syncthreads();
    wr = f1W + k * 256;
    a = f1b[k];
    for (int c = 0; c < 256; c++) a += wr[c] * h1[c];
    h2[k] = fmaxf(a, 0.f);
    __syncthreads();
    if (k < 32) {
        wr = f2W + k * 256;
        a = f2b[k];
        for (int c = 0; c < 256; c++) a += wr[c] * h2[c];
        out[n * 32 + k] = a;
    }
}

extern "C" void kernel_launch(void* const* d_in, const int* in_sizes, int n_in,
                              void* d_out, int out_size, void* d_ws, size_t ws_size,
                              hipStream_t stream)
{
    const int*   questions = (const int*)  d_in[0];
    const float* images = (const float*)d_in[1];
    const float* embW   = (const float*)d_in[2];
    const float* Wih    = (const float*)d_in[3];
    const float* Whh    = (const float*)d_in[4];
    const float* bih    = (const float*)d_in[5];
    const float* bhh    = (const float*)d_in[6];
    const float* c0W    = (const float*)d_in[7];
    const float* c0b    = (const float*)d_in[8];
    const float* bn0g   = (const float*)d_in[9];
    const float* bn0b   = (const float*)d_in[10];
    const float* csW    = (const float*)d_in[11];
    const float* csb    = (const float*)d_in[12];
    const float* bnsg   = (const float*)d_in[13];
    const float* bnsb   = (const float*)d_in[14];
    const float* g0W    = (const float*)d_in[15];
    const float* g0b    = (const float*)d_in[16];
    const float* gsW    = (const float*)d_in[17];
    const float* gsb    = (const float*)d_in[18];
    const float* f0W    = (const float*)d_in[19];
    const float* f0b    = (const float*)d_in[20];
    const float* f1W    = (const float*)d_in[21];
    const float* f1b    = (const float*)d_in[22];
    const float* f2W    = (const float*)d_in[23];
    const float* f2b    = (const float*)d_in[24];

    float* ws  = (float*)d_ws;
    float* out = (float*)d_out;

    // workspace layout (floats)
    float* conv0o = ws;                 // 3,145,728  (32,24,64,64)
    float* conv1o = ws + 3145728;       //   786,432  (32,24,32,32)
    float* conv2o = ws + 3932160;       //   196,608  (32,24,16,16)
    float* conv3o = ws + 4128768;       //    49,152  (32,24,8,8)
    float* stats  = ws + 4177920;       //       192  (4 layers x 24ch x {sum,sumsq})
    float* qf     = ws + 4178112;       //     4,096  (32,128)
    // overlay into conv0o region (dead after conv1 consumes it):
    float* Abuf   = ws;                 //   524,288  (32,64,256)
    float* Bbuf   = ws + 524288;        //   524,288
    float* QTb    = ws + 1048576;       //     8,192  (32,256)
    unsigned short* Wbf = (unsigned short*)(ws + 1056768);  // 196,608 bf16
    float* part   = ws + 1155072;       //   524,288  (2048,256)

    hipMemsetAsync(stats, 0, 192 * sizeof(float), stream);

    lstm_kernel<<<32, 512, 0, stream>>>(questions, embW, Wih, Whh, bih, bhh, qf);

    conv_s2<3, 256><<<12288, 256, 0, stream>>>(images, c0W, c0b, conv0o, stats,
                                               24, 128, 128, 64, 64);
    bn_relu<<<12288, 256, 0, stream>>>(conv0o, stats, bn0g, bn0b,
                                       24, 4096, 3145728, 1.f / 131072.f);
    conv_s2<24, 256><<<3072, 256, 0, stream>>>(conv0o, csW, csb, conv1o, stats + 48,
                                               24, 64, 64, 32, 32);
    cvt_bf16<<<768, 256, 0, stream>>>(gsW, Wbf, 196608);   // conv0o now dead
    bn_relu<<<3072, 256, 0, stream>>>(conv1o, stats + 48, bnsg, bnsb,
                                      24, 1024, 786432, 1.f / 32768.f);
    conv_s2<24, 256><<<768, 256, 0, stream>>>(conv1o, csW + 5184, csb + 24, conv2o,
                                              stats + 96, 24, 32, 32, 16, 16);
    bn_relu<<<768, 256, 0, stream>>>(conv2o, stats + 96, bnsg + 24, bnsb + 24,
                                     24, 256, 196608, 1.f / 8192.f);
    conv_s2<24, 64><<<768, 64, 0, stream>>>(conv2o, csW + 10368, csb + 48, conv3o,
                                            stats + 144, 24, 16, 16, 8, 8);
    bn_relu<<<192, 256, 0, stream>>>(conv3o, stats + 144, bnsg + 48, bnsb + 48,
                                     24, 64, 49152, 1.f / 2048.f);

    abqt_kernel<<<2048, 256, 0, stream>>>(conv3o, qf, g0W, g0b, Abuf, Bbuf, QTb);
    gs_fused<<<2048, 256, 0, stream>>>(Abuf, Bbuf, QTb, Wbf, gsb, part);
    f_mlp<<<32, 256, 0, stream>>>(part, f0W, f0b, f1W, f1b, f2W, f2b, out);
}

// Round 2
// 404.737 us; speedup vs baseline: 1.5268x; 1.5268x over previous
//
#include <hip/hip_runtime.h>

// ---------- model dims ----------
#define NB   32
#define TT   46
#define RNN  128
#define CDIM 24
#define GD   256
#define GIN  180

typedef __attribute__((ext_vector_type(8))) short  bf16x8;
typedef __attribute__((ext_vector_type(4))) short  s16x4;
typedef __attribute__((ext_vector_type(8))) unsigned short u16x8;
typedef __attribute__((ext_vector_type(4))) float  f32x4;

__device__ __forceinline__ unsigned short f2bf(float v) {
    unsigned u = __float_as_uint(v);
    u = u + 0x7fffu + ((u >> 16) & 1u);   // RNE
    return (unsigned short)(u >> 16);
}

// ---------------- LSTM (incl. embedding lookup) ----------------
__global__ __launch_bounds__(512) void lstm_kernel(
    const int* __restrict__ q, const float* __restrict__ embW,
    const float* __restrict__ Wih, const float* __restrict__ Whh,
    const float* __restrict__ bih, const float* __restrict__ bhh,
    float* __restrict__ qf)
{
    const int n = blockIdx.x, tid = threadIdx.x;
    __shared__ float xs[32], hs[RNN], cs[RNN], zg[512];
    float wih[32], whh[RNN];
#pragma unroll
    for (int j = 0; j < 32; j++) wih[j] = Wih[tid * 32 + j];
#pragma unroll
    for (int j = 0; j < RNN; j++) whh[j] = Whh[tid * RNN + j];
    const float bias = bih[tid] + bhh[tid];
    if (tid < RNN) { hs[tid] = 0.f; cs[tid] = 0.f; }
    __syncthreads();
    for (int t = 0; t < TT; t++) {
        if (tid < 32) xs[tid] = embW[q[n * TT + t] * 32 + tid];
        __syncthreads();
        float acc = bias;
#pragma unroll
        for (int j = 0; j < 32; j++) acc += wih[j] * xs[j];
#pragma unroll
        for (int j = 0; j < RNN; j++) acc += whh[j] * hs[j];
        zg[tid] = acc;
        __syncthreads();
        if (tid < RNN) {
            float ig = 1.f / (1.f + expf(-zg[tid]));
            float fg = 1.f / (1.f + expf(-zg[RNN + tid]));
            float gg = tanhf(zg[2 * RNN + tid]);
            float og = 1.f / (1.f + expf(-zg[3 * RNN + tid]));
            float cn = fg * cs[tid] + ig * gg;
            cs[tid] = cn;
            hs[tid] = og * tanhf(cn);
        }
        __syncthreads();
    }
    if (tid < RNN) qf[n * RNN + tid] = hs[tid];
}

// ---------------- tiled conv 3x3 s2 p1: LDS input tile, all 24 co per block ----------------
// thread = (pixel, co-group); weights via wave-uniform s_load; fused BN(prev)+ReLU on load;
// fused BN-stat partials (shfl reduce + 1 atomic per channel per block)
template<int CIN, int TILE, bool BNIN>
__global__ __launch_bounds__(256) void conv_tiled(
    const float* __restrict__ in, const float* __restrict__ Wg,
    const float* __restrict__ bias,
    const float* __restrict__ pstats, const float* __restrict__ pg,
    const float* __restrict__ pb, float pinvM,
    float* __restrict__ out, float* __restrict__ stats,
    int HIN, int WIN, int HO, int WO, int tilesX)
{
    constexpr int NPIX = TILE * TILE;               // 256 or 64
    constexpr int COPT = (NPIX >= 256) ? 24 : 6;    // channels per thread
    constexpr int WPC  = (NPIX + 63) / 64;          // waves per co-group
    constexpr int S  = 2 * TILE + 1;
    constexpr int SP = S + 1;
    __shared__ float in_t[CIN][S][SP];
    __shared__ float r1s[4][COPT], r2s[4][COPT];
    __shared__ float sc[CIN], sh[CIN];
    const int tid = threadIdx.x;
    const int tx = blockIdx.x % tilesX;
    const int ty = (blockIdx.x / tilesX) % tilesX;
    const int n  = blockIdx.x / (tilesX * tilesX);

    if (BNIN) {
        if (tid < CIN) {
            float mu  = pstats[2 * tid] * pinvM;
            float var = pstats[2 * tid + 1] * pinvM - mu * mu;
            float rs  = rsqrtf(var + 1e-5f);
            sc[tid] = rs * pg[tid];
            sh[tid] = pb[tid] - mu * rs * pg[tid];
        }
        __syncthreads();
    }
    const int iy0 = ty * 2 * TILE - 1, ix0 = tx * 2 * TILE - 1;
    for (int idx = tid; idx < CIN * S * S; idx += 256) {
        int ci = idx / (S * S), r = idx % (S * S);
        int ry = r / S, rx = r % S;
        int gy = iy0 + ry, gx = ix0 + rx;
        float v = 0.f;
        if ((unsigned)gy < (unsigned)HIN && (unsigned)gx < (unsigned)WIN) {
            v = in[((size_t)(n * CIN + ci) * HIN + gy) * WIN + gx];
            if (BNIN) v = fmaxf(v * sc[ci] + sh[ci], 0.f);
        }
        in_t[ci][ry][rx] = v;
    }
    __syncthreads();

    const int p   = tid % NPIX;
    const int co0 = __builtin_amdgcn_readfirstlane((tid / NPIX) * COPT);
    const int ly  = (p / TILE) * 2, lx = (p % TILE) * 2;
    float acc[COPT];
#pragma unroll
    for (int c = 0; c < COPT; c++) acc[c] = bias[co0 + c];
    for (int ci = 0; ci < CIN; ci++) {
#pragma unroll
        for (int ky = 0; ky < 3; ky++) {
            const float* row = &in_t[ci][ly + ky][lx];
#pragma unroll
            for (int kx = 0; kx < 3; kx++) {
                float v = row[kx];
#pragma unroll
                for (int c = 0; c < COPT; c++)
                    acc[c] += v * Wg[(((co0 + c) * CIN + ci) * 3 + ky) * 3 + kx];
            }
        }
    }
    const int oy = ty * TILE + p / TILE, ox = tx * TILE + p % TILE;
#pragma unroll
    for (int c = 0; c < COPT; c++)
        out[((size_t)(n * 24 + co0 + c) * HO + oy) * WO + ox] = acc[c];

    // BN-stat partials
    const int lane = tid & 63, wv = tid >> 6;
#pragma unroll
    for (int c = 0; c < COPT; c++) {
        float s1 = acc[c], s2 = acc[c] * acc[c];
#pragma unroll
        for (int off = 1; off < 64; off <<= 1) {
            s1 += __shfl_xor(s1, off, 64);
            s2 += __shfl_xor(s2, off, 64);
        }
        if (lane == 0) { r1s[wv][c] = s1; r2s[wv][c] = s2; }
    }
    __syncthreads();
    if (tid < 24) {
        int cg = tid / COPT, slot = tid % COPT;
        float t1 = 0.f, t2 = 0.f;
#pragma unroll
        for (int u = 0; u < WPC; u++) { t1 += r1s[cg * WPC + u][slot]; t2 += r2s[cg * WPC + u][slot]; }
        atomicAdd(&stats[tid * 2],     t1);
        atomicAdd(&stats[tid * 2 + 1], t2);
    }
}

// ---------------- fp32 -> bf16 convert ----------------
__global__ __launch_bounds__(256) void cvt_bf16(
    const float* __restrict__ src, unsigned short* __restrict__ dst, int n)
{
    int i = blockIdx.x * 256 + threadIdx.x;
    if (i < n) dst[i] = f2bf(src[i]);
}

// ---------------- per-object projections A,B and question term QT ----------------
// applies BN(conv3 stats)+ReLU on the fly to the raw conv3 output
__global__ __launch_bounds__(256) void abqt_kernel(
    const float* __restrict__ feat,  // (32,24,8,8) raw conv3
    const float* __restrict__ stats, const float* __restrict__ g,
    const float* __restrict__ b, float invM,
    const float* __restrict__ qf,    // (32,128)
    const float* __restrict__ g0W,   // (256,180)
    const float* __restrict__ g0b,
    float* __restrict__ A, float* __restrict__ Bm, float* __restrict__ QT)
{
    const int n = blockIdx.x >> 6;
    const int i = blockIdx.x & 63;
    const int k = threadIdx.x;
    __shared__ float obj[26];
    __shared__ float qs[RNN];
    if (k < 24) {
        float mu  = stats[2 * k] * invM;
        float var = stats[2 * k + 1] * invM - mu * mu;
        float rs  = rsqrtf(var + 1e-5f);
        float v = feat[((n * CDIM + k) * 8 + (i >> 3)) * 8 + (i & 7)];
        v = (v - mu) * rs * g[k] + b[k];
        obj[k] = fmaxf(v, 0.f);
    }
    else if (k == 24) obj[24] = (float)(i & 7)  * (1.f / 7.f);   // xc
    else if (k == 25) obj[25] = (float)(i >> 3) * (1.f / 7.f);   // yc
    if (k >= 128) qs[k - 128] = qf[n * RNN + (k - 128)];
    __syncthreads();
    const float* wr = g0W + k * GIN;
    float a = 0.f, bb = 0.f;
#pragma unroll
    for (int c = 0; c < 26; c++) { a += wr[c] * obj[c]; bb += wr[26 + c] * obj[c]; }
    A [(blockIdx.x << 8) + k] = a;
    Bm[(blockIdx.x << 8) + k] = bb;
    if (i == 0) {
        float qv = g0b[k];
#pragma unroll
        for (int d = 0; d < RNN; d++) qv += wr[52 + d] * qs[d];
        QT[(n << 8) + k] = qv;
    }
}

// ---------------- fused 3x(256->256) g-MLP + pair sum, bf16 MFMA ----------------
__global__ __launch_bounds__(256) void gs_fused(
    const float* __restrict__ A, const float* __restrict__ Bm, const float* __restrict__ QT,
    const unsigned short* __restrict__ Wb,   // (3,256,256) bf16
    const float* __restrict__ gsb,           // (3,256)
    float* __restrict__ partial)             // (2048,256)
{
    __shared__ __align__(16) unsigned short Xs[64 * 256];   // 32 KB
    __shared__ __align__(16) unsigned short Wls[256 * 32];  // 16 KB
    __shared__ float AQ[256];
    __shared__ float biasv[3][256];
    const int bb = blockIdx.x, n = bb >> 6, tid = threadIdx.x;
    const int lane = tid & 63, w = tid >> 6, l15 = lane & 15, lh = lane >> 4;

    AQ[tid] = A[(bb << 8) + tid] + QT[(n << 8) + tid];
#pragma unroll
    for (int l = 0; l < 3; l++) biasv[l][tid] = gsb[(l << 8) + tid];
    __syncthreads();

#pragma unroll
    for (int it = 0; it < 8; it++) {
        int task = tid + (it << 8);
        int j = task >> 5, g = task & 31;
        const f32x4* bp = (const f32x4*)(Bm + (((n << 6) + j) << 8) + (g << 3));
        f32x4 b0 = bp[0], b1 = bp[1];
        u16x8 pk;
        int c0 = g << 3;
#pragma unroll
        for (int p = 0; p < 4; p++) {
            pk[p]     = f2bf(fmaxf(b0[p] + AQ[c0 + p], 0.f));
            pk[p + 4] = f2bf(fmaxf(b1[p] + AQ[c0 + 4 + p], 0.f));
        }
        *(u16x8*)((char*)Xs + j * 512 + ((g ^ (j & 7)) << 4)) = pk;
    }

    f32x4 acc[4][4];
    const f32x4 zero4 = {0.f, 0.f, 0.f, 0.f};
    for (int layer = 0; layer < 3; layer++) {
#pragma unroll
        for (int tc = 0; tc < 4; tc++)
#pragma unroll
            for (int sl = 0; sl < 4; sl++) acc[tc][sl] = zero4;
        const unsigned short* Wl = Wb + (layer << 16);
        for (int kb = 0; kb < 8; kb++) {
            __syncthreads();
            {
                const f32x4* src = (const f32x4*)(Wl + (tid << 8) + (kb << 5));
                char* drow = (char*)Wls + (tid << 6);
                int sw = (tid >> 1) & 3;
#pragma unroll
                for (int u = 0; u < 4; u++) *(f32x4*)(drow + ((u ^ sw) << 4)) = src[u];
            }
            __syncthreads();
            bf16x8 wf[4], xf[4];
#pragma unroll
            for (int tc = 0; tc < 4; tc++) {
                int ko = (w << 6) + (tc << 4) + l15;
                int bu = lh ^ ((ko >> 1) & 3);
                wf[tc] = *(const bf16x8*)((const char*)Wls + (ko << 6) + (bu << 4));
            }
#pragma unroll
            for (int sl = 0; sl < 4; sl++) {
                int ar = (sl << 4) + l15;
                int au = ((kb << 2) + lh) ^ (ar & 7);
                xf[sl] = *(const bf16x8*)((const char*)Xs + ar * 512 + (au << 4));
            }
#pragma unroll
            for (int tc = 0; tc < 4; tc++)
#pragma unroll
                for (int sl = 0; sl < 4; sl++)
                    acc[tc][sl] = __builtin_amdgcn_mfma_f32_16x16x32_bf16(
                        wf[tc], xf[sl], acc[tc][sl], 0, 0, 0);
        }
        if (layer < 2) {
            __syncthreads();
#pragma unroll
            for (int tc = 0; tc < 4; tc++) {
                int c0 = (w << 6) + (tc << 4) + (lh << 2);
                float b0 = biasv[layer][c0],     b1 = biasv[layer][c0 + 1];
                float b2 = biasv[layer][c0 + 2], b3 = biasv[layer][c0 + 3];
#pragma unroll
                for (int sl = 0; sl < 4; sl++) {
                    int row = (sl << 4) + l15;
                    s16x4 pk;
                    pk[0] = (short)f2bf(fmaxf(acc[tc][sl][0] + b0, 0.f));
                    pk[1] = (short)f2bf(fmaxf(acc[tc][sl][1] + b1, 0.f));
                    pk[2] = (short)f2bf(fmaxf(acc[tc][sl][2] + b2, 0.f));
                    pk[3] = (short)f2bf(fmaxf(acc[tc][sl][3] + b3, 0.f));
                    *(s16x4*)((char*)Xs + row * 512 + (((c0 >> 3) ^ (row & 7)) << 4)
                              + ((c0 & 7) << 1)) = pk;
                }
            }
        } else {
#pragma unroll
            for (int tc = 0; tc < 4; tc++) {
                int c0 = (w << 6) + (tc << 4) + (lh << 2);
                f32x4 cs;
#pragma unroll
                for (int p = 0; p < 4; p++) {
                    float bv = biasv[2][c0 + p];
                    float s = 0.f;
#pragma unroll
                    for (int sl = 0; sl < 4; sl++) s += fmaxf(acc[tc][sl][p] + bv, 0.f);
                    s += __shfl_xor(s, 1, 64);
                    s += __shfl_xor(s, 2, 64);
                    s += __shfl_xor(s, 4, 64);
                    s += __shfl_xor(s, 8, 64);
                    cs[p] = s;
                }
                if (l15 == 0) *(f32x4*)(partial + (size_t)bb * 256 + c0) = cs;
            }
        }
    }
}

// ---------------- f-MLP ----------------
__global__ __launch_bounds__(256) void f_mlp(
    const float* __restrict__ partial,
    const float* __restrict__ f0W, const float* __restrict__ f0b,
    const float* __restrict__ f1W, const float* __restrict__ f1b,
    const float* __restrict__ f2W, const float* __restrict__ f2b,
    float* __restrict__ out)
{
    const int n = blockIdx.x, k = threadIdx.x;
    __shared__ float fin[256], h1[256], h2[256];
    float s = 0.f;
    for (int b = 0; b < 64; b++) s += partial[(size_t)(n * 64 + b) * 256 + k];
    fin[k] = s;
    __syncthreads();
    const float* wr = f0W + k * 256;
    float a = f0b[k];
    for (int c = 0; c < 256; c++) a += wr[c] * fin[c];
    h1[k] = fmaxf(a, 0.f);
    __syncthreads();
    wr = f1W + k * 256;
    a = f1b[k];
    for (int c = 0; c < 256; c++) a += wr[c] * h1[c];
    h2[k] = fmaxf(a, 0.f);
    __syncthreads();
    if (k < 32) {
        wr = f2W + k * 256;
        a = f2b[k];
        for (int c = 0; c < 256; c++) a += wr[c] * h2[c];
        out[n * 32 + k] = a;
    }
}

extern "C" void kernel_launch(void* const* d_in, const int* in_sizes, int n_in,
                              void* d_out, int out_size, void* d_ws, size_t ws_size,
                              hipStream_t stream)
{
    const int*   questions = (const int*)  d_in[0];
    const float* images = (const float*)d_in[1];
    const float* embW   = (const float*)d_in[2];
    const float* Wih    = (const float*)d_in[3];
    const float* Whh    = (const float*)d_in[4];
    const float* bih    = (const float*)d_in[5];
    const float* bhh    = (const float*)d_in[6];
    const float* c0W    = (const float*)d_in[7];
    const float* c0b    = (const float*)d_in[8];
    const float* bn0g   = (const float*)d_in[9];
    const float* bn0b   = (const float*)d_in[10];
    const float* csW    = (const float*)d_in[11];
    const float* csb    = (const float*)d_in[12];
    const float* bnsg   = (const float*)d_in[13];
    const float* bnsb   = (const float*)d_in[14];
    const float* g0W    = (const float*)d_in[15];
    const float* g0b    = (const float*)d_in[16];
    const float* gsW    = (const float*)d_in[17];
    const float* gsb    = (const float*)d_in[18];
    const float* f0W    = (const float*)d_in[19];
    const float* f0b    = (const float*)d_in[20];
    const float* f1W    = (const float*)d_in[21];
    const float* f1b    = (const float*)d_in[22];
    const float* f2W    = (const float*)d_in[23];
    const float* f2b    = (const float*)d_in[24];

    float* ws  = (float*)d_ws;
    float* out = (float*)d_out;

    // workspace layout (floats)
    float* conv0o = ws;                 // 3,145,728  (32,24,64,64)
    float* conv1o = ws + 3145728;       //   786,432  (32,24,32,32)
    float* conv2o = ws + 3932160;       //   196,608  (32,24,16,16)
    float* conv3o = ws + 4128768;       //    49,152  (32,24,8,8)
    float* stats  = ws + 4177920;       //       192
    float* qf     = ws + 4178112;       //     4,096  (32,128)
    // overlay into conv0o region (dead after conv1 consumes it):
    float* Abuf   = ws;                 //   524,288  (32,64,256)
    float* Bbuf   = ws + 524288;        //   524,288
    float* QTb    = ws + 1048576;       //     8,192  (32,256)
    unsigned short* Wbf = (unsigned short*)(ws + 1056768);  // 196,608 bf16
    float* part   = ws + 1155072;       //   524,288  (2048,256)

    hipMemsetAsync(stats, 0, 192 * sizeof(float), stream);

    lstm_kernel<<<32, 512, 0, stream>>>(questions, embW, Wih, Whh, bih, bhh, qf);

    // conv0: in (32,3,128,128) -> out (32,24,64,64); 16x16 tiles, 4x4 grid
    conv_tiled<3, 16, false><<<512, 256, 0, stream>>>(
        images, c0W, c0b, nullptr, nullptr, nullptr, 0.f,
        conv0o, stats, 128, 128, 64, 64, 4);
    // conv1: BN0 applied on load; out (32,24,32,32); 8x8 tiles, 4x4 grid
    conv_tiled<24, 8, true><<<512, 256, 0, stream>>>(
        conv0o, csW, csb, stats, bn0g, bn0b, 1.f / 131072.f,
        conv1o, stats + 48, 64, 64, 32, 32, 4);
    cvt_bf16<<<768, 256, 0, stream>>>(gsW, Wbf, 196608);   // conv0o now dead
    // conv2: out (32,24,16,16); 2x2 grid
    conv_tiled<24, 8, true><<<128, 256, 0, stream>>>(
        conv1o, csW + 5184, csb + 24, stats + 48, bnsg, bnsb, 1.f / 32768.f,
        conv2o, stats + 96, 32, 32, 16, 16, 2);
    // conv3: out (32,24,8,8); 1x1 grid
    conv_tiled<24, 8, true><<<32, 256, 0, stream>>>(
        conv2o, csW + 10368, csb + 48, stats + 96, bnsg + 24, bnsb + 24, 1.f / 8192.f,
        conv3o, stats + 144, 16, 16, 8, 8, 1);

    abqt_kernel<<<2048, 256, 0, stream>>>(conv3o, stats + 144, bnsg + 48, bnsb + 48,
                                          1.f / 2048.f, qf, g0W, g0b, Abuf, Bbuf, QTb);
    gs_fused<<<2048, 256, 0, stream>>>(Abuf, Bbuf, QTb, Wbf, gsb, part);
    f_mlp<<<32, 256, 0, stream>>>(part, f0W, f0b, f1W, f1b, f2W, f2b, out);
}

// Round 3
// 370.820 us; speedup vs baseline: 1.6664x; 1.0915x over previous
//
#include <hip/hip_runtime.h>

// ---------- model dims ----------
#define NB   32
#define TT   46
#define RNN  128
#define CDIM 24
#define GD   256
#define GIN  180

typedef __attribute__((ext_vector_type(8))) short  bf16x8;
typedef __attribute__((ext_vector_type(4))) short  s16x4;
typedef __attribute__((ext_vector_type(8))) unsigned short u16x8;
typedef __attribute__((ext_vector_type(4))) float  f32x4;

__device__ __forceinline__ unsigned short f2bf(float v) {
    unsigned u = __float_as_uint(v);
    u = u + 0x7fffu + ((u >> 16) & 1u);   // RNE
    return (unsigned short)(u >> 16);
}

// ---------------- LSTM (incl. embedding lookup) ----------------
__global__ __launch_bounds__(512) void lstm_kernel(
    const int* __restrict__ q, const float* __restrict__ embW,
    const float* __restrict__ Wih, const float* __restrict__ Whh,
    const float* __restrict__ bih, const float* __restrict__ bhh,
    float* __restrict__ qf)
{
    const int n = blockIdx.x, tid = threadIdx.x;
    __shared__ float xs[32], hs[RNN], cs[RNN], zg[512];
    float wih[32], whh[RNN];
#pragma unroll
    for (int j = 0; j < 32; j++) wih[j] = Wih[tid * 32 + j];
#pragma unroll
    for (int j = 0; j < RNN; j++) whh[j] = Whh[tid * RNN + j];
    const float bias = bih[tid] + bhh[tid];
    if (tid < RNN) { hs[tid] = 0.f; cs[tid] = 0.f; }
    __syncthreads();
    for (int t = 0; t < TT; t++) {
        if (tid < 32) xs[tid] = embW[q[n * TT + t] * 32 + tid];
        __syncthreads();
        float acc = bias;
#pragma unroll
        for (int j = 0; j < 32; j++) acc += wih[j] * xs[j];
#pragma unroll
        for (int j = 0; j < RNN; j++) acc += whh[j] * hs[j];
        zg[tid] = acc;
        __syncthreads();
        if (tid < RNN) {
            float ig = 1.f / (1.f + expf(-zg[tid]));
            float fg = 1.f / (1.f + expf(-zg[RNN + tid]));
            float gg = tanhf(zg[2 * RNN + tid]);
            float og = 1.f / (1.f + expf(-zg[3 * RNN + tid]));
            float cn = fg * cs[tid] + ig * gg;
            cs[tid] = cn;
            hs[tid] = og * tanhf(cn);
        }
        __syncthreads();
    }
    if (tid < RNN) qf[n * RNN + tid] = hs[tid];
}

// ---------------- tiled conv 3x3 s2 p1 ----------------
template<int CIN, int TILE, bool BNIN>
__global__ __launch_bounds__(256) void conv_tiled(
    const float* __restrict__ in, const float* __restrict__ Wg,
    const float* __restrict__ bias,
    const float* __restrict__ pstats, const float* __restrict__ pg,
    const float* __restrict__ pb, float pinvM,
    float* __restrict__ out, float* __restrict__ stats,
    int HIN, int WIN, int HO, int WO, int tilesX)
{
    constexpr int NPIX = TILE * TILE;
    constexpr int COPT = (NPIX >= 256) ? 24 : 6;
    constexpr int WPC  = (NPIX + 63) / 64;
    constexpr int S  = 2 * TILE + 1;
    constexpr int SP = S + 1;
    __shared__ float in_t[CIN][S][SP];
    __shared__ float r1s[4][COPT], r2s[4][COPT];
    __shared__ float sc[CIN], sh[CIN];
    const int tid = threadIdx.x;
    const int tx = blockIdx.x % tilesX;
    const int ty = (blockIdx.x / tilesX) % tilesX;
    const int n  = blockIdx.x / (tilesX * tilesX);

    if (BNIN) {
        if (tid < CIN) {
            float mu  = pstats[2 * tid] * pinvM;
            float var = pstats[2 * tid + 1] * pinvM - mu * mu;
            float rs  = rsqrtf(var + 1e-5f);
            sc[tid] = rs * pg[tid];
            sh[tid] = pb[tid] - mu * rs * pg[tid];
        }
        __syncthreads();
    }
    const int iy0 = ty * 2 * TILE - 1, ix0 = tx * 2 * TILE - 1;
    for (int idx = tid; idx < CIN * S * S; idx += 256) {
        int ci = idx / (S * S), r = idx % (S * S);
        int ry = r / S, rx = r % S;
        int gy = iy0 + ry, gx = ix0 + rx;
        float v = 0.f;
        if ((unsigned)gy < (unsigned)HIN && (unsigned)gx < (unsigned)WIN) {
            v = in[((size_t)(n * CIN + ci) * HIN + gy) * WIN + gx];
            if (BNIN) v = fmaxf(v * sc[ci] + sh[ci], 0.f);
        }
        in_t[ci][ry][rx] = v;
    }
    __syncthreads();

    const int p   = tid % NPIX;
    const int co0 = __builtin_amdgcn_readfirstlane((tid / NPIX) * COPT);
    const int ly  = (p / TILE) * 2, lx = (p % TILE) * 2;
    float acc[COPT];
#pragma unroll
    for (int c = 0; c < COPT; c++) acc[c] = bias[co0 + c];
    for (int ci = 0; ci < CIN; ci++) {
#pragma unroll
        for (int ky = 0; ky < 3; ky++) {
            const float* row = &in_t[ci][ly + ky][lx];
#pragma unroll
            for (int kx = 0; kx < 3; kx++) {
                float v = row[kx];
#pragma unroll
                for (int c = 0; c < COPT; c++)
                    acc[c] += v * Wg[(((co0 + c) * CIN + ci) * 3 + ky) * 3 + kx];
            }
        }
    }
    const int oy = ty * TILE + p / TILE, ox = tx * TILE + p % TILE;
#pragma unroll
    for (int c = 0; c < COPT; c++)
        out[((size_t)(n * 24 + co0 + c) * HO + oy) * WO + ox] = acc[c];

    const int lane = tid & 63, wv = tid >> 6;
#pragma unroll
    for (int c = 0; c < COPT; c++) {
        float s1 = acc[c], s2 = acc[c] * acc[c];
#pragma unroll
        for (int off = 1; off < 64; off <<= 1) {
            s1 += __shfl_xor(s1, off, 64);
            s2 += __shfl_xor(s2, off, 64);
        }
        if (lane == 0) { r1s[wv][c] = s1; r2s[wv][c] = s2; }
    }
    __syncthreads();
    if (tid < 24) {
        int cg = tid / COPT, slot = tid % COPT;
        float t1 = 0.f, t2 = 0.f;
#pragma unroll
        for (int u = 0; u < WPC; u++) { t1 += r1s[cg * WPC + u][slot]; t2 += r2s[cg * WPC + u][slot]; }
        atomicAdd(&stats[tid * 2],     t1);
        atomicAdd(&stats[tid * 2 + 1], t2);
    }
}

// ---------------- fp32 -> bf16 convert ----------------
__global__ __launch_bounds__(256) void cvt_bf16(
    const float* __restrict__ src, unsigned short* __restrict__ dst, int n)
{
    int i = blockIdx.x * 256 + threadIdx.x;
    if (i < n) dst[i] = f2bf(src[i]);
}

// ---------------- A,B,QT projections: one block per n ----------------
__global__ __launch_bounds__(256) void abqt_kernel(
    const float* __restrict__ feat,  // (32,24,8,8) raw conv3
    const float* __restrict__ stats, const float* __restrict__ g,
    const float* __restrict__ b, float invM,
    const float* __restrict__ qf,    // (32,128)
    const float* __restrict__ g0W,   // (256,180)
    const float* __restrict__ g0b,
    float* __restrict__ A, float* __restrict__ Bm, float* __restrict__ QT)
{
    const int n = blockIdx.x, k = threadIdx.x;
    __shared__ float obj[64][27];
    __shared__ float qs[RNN];
    __shared__ float sc[24], sh[24];
    if (k < 24) {
        float mu  = stats[2 * k] * invM;
        float var = stats[2 * k + 1] * invM - mu * mu;
        float rs  = rsqrtf(var + 1e-5f);
        sc[k] = rs * g[k];
        sh[k] = b[k] - mu * rs * g[k];
    }
    if (k >= 128) qs[k - 128] = qf[n * RNN + (k - 128)];
    __syncthreads();
    for (int idx = k; idx < 24 * 64; idx += 256) {
        int c = idx >> 6, i = idx & 63;
        float v = feat[(n * CDIM + c) * 64 + i];
        obj[i][c] = fmaxf(v * sc[c] + sh[c], 0.f);
    }
    if (k < 64) {
        obj[k][24] = (float)(k & 7)  * (1.f / 7.f);   // xc
        obj[k][25] = (float)(k >> 3) * (1.f / 7.f);   // yc
    }
    __syncthreads();
    const float* wr = g0W + k * GIN;
    float wA[26], wB[26];
#pragma unroll
    for (int c = 0; c < 26; c++) { wA[c] = wr[c]; wB[c] = wr[26 + c]; }
    float qv = g0b[k];
#pragma unroll
    for (int d = 0; d < RNN; d++) qv += wr[52 + d] * qs[d];
    QT[(n << 8) + k] = qv;
    for (int i = 0; i < 64; i++) {
        float a = 0.f, bb = 0.f;
#pragma unroll
        for (int c = 0; c < 26; c++) { a += wA[c] * obj[i][c]; bb += wB[c] * obj[i][c]; }
        A [(((n << 6) + i) << 8) + k] = a;
        Bm[(((n << 6) + i) << 8) + k] = bb;
    }
}

// ---------------- fused 3x(256->256) g-MLP + pair sum, bf16 MFMA ----------------
// block = (n, i-pair): 128 pair-rows; X in LDS (bf16, XOR-swizzled);
// W direct global->reg, register double-buffered; 6 barriers total
__global__ __launch_bounds__(256) void gs_fused(
    const float* __restrict__ A, const float* __restrict__ Bm, const float* __restrict__ QT,
    const unsigned short* __restrict__ Wb,   // (3,256,256) bf16
    const float* __restrict__ gsb,           // (3,256)
    float* __restrict__ partial)             // (1024,256)
{
    __shared__ __align__(16) unsigned short Xs[128 * 256];  // 64 KB
    __shared__ float AQ[2][256];
    __shared__ float biasv[3][256];
    const int bb = blockIdx.x, n = bb >> 5, ip = bb & 31, tid = threadIdx.x;
    const int lane = tid & 63, w = tid >> 6, l15 = lane & 15, lh = lane >> 4;

    {
        float qt = QT[(n << 8) + tid];
        AQ[0][tid] = A[((((n << 6) + ip * 2)     ) << 8) + tid] + qt;
        AQ[1][tid] = A[((((n << 6) + ip * 2 + 1) ) << 8) + tid] + qt;
    }
#pragma unroll
    for (int l = 0; l < 3; l++) biasv[l][tid] = gsb[(l << 8) + tid];
    __syncthreads();

    // build h0 = relu(A_i + B_j + QT) into Xs; 128 rows x 32 col-groups
#pragma unroll
    for (int it = 0; it < 16; it++) {
        int task = tid + (it << 8);
        int r = task >> 5, g = task & 31;
        int isub = r >> 6, j = r & 63;
        const f32x4* bp = (const f32x4*)(Bm + (((n << 6) + j) << 8) + (g << 3));
        f32x4 b0 = bp[0], b1 = bp[1];
        u16x8 pk;
        int c0 = g << 3;
#pragma unroll
        for (int p = 0; p < 4; p++) {
            pk[p]     = f2bf(fmaxf(b0[p] + AQ[isub][c0 + p], 0.f));
            pk[p + 4] = f2bf(fmaxf(b1[p] + AQ[isub][c0 + 4 + p], 0.f));
        }
        *(u16x8*)((char*)Xs + r * 512 + ((g ^ (r & 7)) << 4)) = pk;
    }

    f32x4 acc[4][8];                 // [col-tile][row-slab]
    const f32x4 zero4 = {0.f, 0.f, 0.f, 0.f};
    for (int layer = 0; layer < 3; layer++) {
#pragma unroll
        for (int tc = 0; tc < 4; tc++)
#pragma unroll
            for (int sl = 0; sl < 8; sl++) acc[tc][sl] = zero4;
        // per-lane W base: row ko=(w*64+tc*16+l15), k offset lh*8 (+kb*32)
        const unsigned short* wbase = Wb + (layer << 16)
                                    + ((((w << 6) + l15)) << 8) + (lh << 3);
        bf16x8 wa[4], wn[4];
#pragma unroll
        for (int tc = 0; tc < 4; tc++) wa[tc] = *(const bf16x8*)(wbase + (tc << 12));
        __syncthreads();   // Xs ready (build or previous writeback)
#pragma unroll
        for (int kb = 0; kb < 8; kb++) {
            if (kb < 7) {
#pragma unroll
                for (int tc = 0; tc < 4; tc++)
                    wn[tc] = *(const bf16x8*)(wbase + (tc << 12) + ((kb + 1) << 5));
            }
            bf16x8 xf[8];
#pragma unroll
            for (int sl = 0; sl < 8; sl++) {
                int ar = (sl << 4) + l15;
                int au = ((kb << 2) + lh) ^ (ar & 7);
                xf[sl] = *(const bf16x8*)((const char*)Xs + ar * 512 + (au << 4));
            }
#pragma unroll
            for (int tc = 0; tc < 4; tc++)
#pragma unroll
                for (int sl = 0; sl < 8; sl++)
                    acc[tc][sl] = __builtin_amdgcn_mfma_f32_16x16x32_bf16(
                        wa[tc], xf[sl], acc[tc][sl], 0, 0, 0);
            if (kb < 7) {
#pragma unroll
                for (int tc = 0; tc < 4; tc++) wa[tc] = wn[tc];
            }
        }
        if (layer < 2) {
            __syncthreads();  // all waves done reading Xs before overwrite
#pragma unroll
            for (int tc = 0; tc < 4; tc++) {
                int c0 = (w << 6) + (tc << 4) + (lh << 2);
                float b0 = biasv[layer][c0],     b1 = biasv[layer][c0 + 1];
                float b2 = biasv[layer][c0 + 2], b3 = biasv[layer][c0 + 3];
#pragma unroll
                for (int sl = 0; sl < 8; sl++) {
                    int row = (sl << 4) + l15;
                    s16x4 pk;
                    pk[0] = (short)f2bf(fmaxf(acc[tc][sl][0] + b0, 0.f));
                    pk[1] = (short)f2bf(fmaxf(acc[tc][sl][1] + b1, 0.f));
                    pk[2] = (short)f2bf(fmaxf(acc[tc][sl][2] + b2, 0.f));
                    pk[3] = (short)f2bf(fmaxf(acc[tc][sl][3] + b3, 0.f));
                    *(s16x4*)((char*)Xs + row * 512 + (((c0 >> 3) ^ (row & 7)) << 4)
                              + ((c0 & 7) << 1)) = pk;
                }
            }
        } else {
            // final: relu + sum over the block's 128 pair-rows -> partial[bb][col]
#pragma unroll
            for (int tc = 0; tc < 4; tc++) {
                int c0 = (w << 6) + (tc << 4) + (lh << 2);
                f32x4 cs;
#pragma unroll
                for (int p = 0; p < 4; p++) {
                    float bv = biasv[2][c0 + p];
                    float s = 0.f;
#pragma unroll
                    for (int sl = 0; sl < 8; sl++) s += fmaxf(acc[tc][sl][p] + bv, 0.f);
                    s += __shfl_xor(s, 1, 64);
                    s += __shfl_xor(s, 2, 64);
                    s += __shfl_xor(s, 4, 64);
                    s += __shfl_xor(s, 8, 64);
                    cs[p] = s;
                }
                if (l15 == 0) *(f32x4*)(partial + (size_t)bb * 256 + c0) = cs;
            }
        }
    }
}

// ---------------- f-MLP ----------------
__global__ __launch_bounds__(256) void f_mlp(
    const float* __restrict__ partial,
    const float* __restrict__ f0W, const float* __restrict__ f0b,
    const float* __restrict__ f1W, const float* __restrict__ f1b,
    const float* __restrict__ f2W, const float* __restrict__ f2b,
    float* __restrict__ out)
{
    const int n = blockIdx.x, k = threadIdx.x;
    __shared__ float fin[256], h1[256], h2[256];
    float s = 0.f;
    for (int b = 0; b < 32; b++) s += partial[(size_t)(n * 32 + b) * 256 + k];
    fin[k] = s;
    __syncthreads();
    const float* wr = f0W + k * 256;
    float a = f0b[k];
    for (int c = 0; c < 256; c++) a += wr[c] * fin[c];
    h1[k] = fmaxf(a, 0.f);
    __syncthreads();
    wr = f1W + k * 256;
    a = f1b[k];
    for (int c = 0; c < 256; c++) a += wr[c] * h1[c];
    h2[k] = fmaxf(a, 0.f);
    __syncthreads();
    if (k < 32) {
        wr = f2W + k * 256;
        a = f2b[k];
        for (int c = 0; c < 256; c++) a += wr[c] * h2[c];
        out[n * 32 + k] = a;
    }
}

extern "C" void kernel_launch(void* const* d_in, const int* in_sizes, int n_in,
                              void* d_out, int out_size, void* d_ws, size_t ws_size,
                              hipStream_t stream)
{
    const int*   questions = (const int*)  d_in[0];
    const float* images = (const float*)d_in[1];
    const float* embW   = (const float*)d_in[2];
    const float* Wih    = (const float*)d_in[3];
    const float* Whh    = (const float*)d_in[4];
    const float* bih    = (const float*)d_in[5];
    const float* bhh    = (const float*)d_in[6];
    const float* c0W    = (const float*)d_in[7];
    const float* c0b    = (const float*)d_in[8];
    const float* bn0g   = (const float*)d_in[9];
    const float* bn0b   = (const float*)d_in[10];
    const float* csW    = (const float*)d_in[11];
    const float* csb    = (const float*)d_in[12];
    const float* bnsg   = (const float*)d_in[13];
    const float* bnsb   = (const float*)d_in[14];
    const float* g0W    = (const float*)d_in[15];
    const float* g0b    = (const float*)d_in[16];
    const float* gsW    = (const float*)d_in[17];
    const float* gsb    = (const float*)d_in[18];
    const float* f0W    = (const float*)d_in[19];
    const float* f0b    = (const float*)d_in[20];
    const float* f1W    = (const float*)d_in[21];
    const float* f1b    = (const float*)d_in[22];
    const float* f2W    = (const float*)d_in[23];
    const float* f2b    = (const float*)d_in[24];

    float* ws  = (float*)d_ws;
    float* out = (float*)d_out;

    // workspace layout (floats)
    float* conv0o = ws;                 // 3,145,728  (32,24,64,64)
    float* conv1o = ws + 3145728;       //   786,432  (32,24,32,32)
    float* conv2o = ws + 3932160;       //   196,608  (32,24,16,16)
    float* conv3o = ws + 4128768;       //    49,152  (32,24,8,8)
    float* stats  = ws + 4177920;       //       192
    float* qf     = ws + 4178112;       //     4,096  (32,128)
    // overlay into conv0o region (dead after conv1 consumes it):
    float* Abuf   = ws;                 //   524,288  (32,64,256)
    float* Bbuf   = ws + 524288;        //   524,288
    float* QTb    = ws + 1048576;       //     8,192  (32,256)
    unsigned short* Wbf = (unsigned short*)(ws + 1056768);  // 196,608 bf16
    float* part   = ws + 1155072;       //   262,144  (1024,256)

    hipMemsetAsync(stats, 0, 192 * sizeof(float), stream);

    lstm_kernel<<<32, 512, 0, stream>>>(questions, embW, Wih, Whh, bih, bhh, qf);

    // conv0: in (32,3,128,128) -> out (32,24,64,64); 16x16 tiles, 4x4 grid
    conv_tiled<3, 16, false><<<512, 256, 0, stream>>>(
        images, c0W, c0b, nullptr, nullptr, nullptr, 0.f,
        conv0o, stats, 128, 128, 64, 64, 4);
    // conv1: BN0 applied on load; out (32,24,32,32); 8x8 tiles, 4x4 grid
    conv_tiled<24, 8, true><<<512, 256, 0, stream>>>(
        conv0o, csW, csb, stats, bn0g, bn0b, 1.f / 131072.f,
        conv1o, stats + 48, 64, 64, 32, 32, 4);
    cvt_bf16<<<768, 256, 0, stream>>>(gsW, Wbf, 196608);   // conv0o now dead
    // conv2: out (32,24,16,16); 2x2 grid
    conv_tiled<24, 8, true><<<128, 256, 0, stream>>>(
        conv1o, csW + 5184, csb + 24, stats + 48, bnsg, bnsb, 1.f / 32768.f,
        conv2o, stats + 96, 32, 32, 16, 16, 2);
    // conv3: out (32,24,8,8); 1x1 grid
    conv_tiled<24, 8, true><<<32, 256, 0, stream>>>(
        conv2o, csW + 10368, csb + 48, stats + 96, bnsg + 24, bnsb + 24, 1.f / 8192.f,
        conv3o, stats + 144, 16, 16, 8, 8, 1);

    abqt_kernel<<<32, 256, 0, stream>>>(conv3o, stats + 144, bnsg + 48, bnsb + 48,
                                        1.f / 2048.f, qf, g0W, g0b, Abuf, Bbuf, QTb);
    gs_fused<<<1024, 256, 0, stream>>>(Abuf, Bbuf, QTb, Wbf, gsb, part);
    f_mlp<<<32, 256, 0, stream>>>(part, f0W, f0b, f1W, f1b, f2W, f2b, out);
}

// Round 4
// 337.662 us; speedup vs baseline: 1.8300x; 1.0982x over previous
//
#include <hip/hip_runtime.h>

// ---------- model dims ----------
#define NB   32
#define TT   46
#define RNN  128
#define CDIM 24
#define GD   256
#define GIN  180

typedef __attribute__((ext_vector_type(8))) short  bf16x8;
typedef __attribute__((ext_vector_type(4))) short  s16x4;
typedef __attribute__((ext_vector_type(8))) unsigned short u16x8;
typedef __attribute__((ext_vector_type(4))) float  f32x4;

__device__ __forceinline__ unsigned short f2bf(float v) {
    unsigned u = __float_as_uint(v);
    u = u + 0x7fffu + ((u >> 16) & 1u);   // RNE
    return (unsigned short)(u >> 16);
}

// ---------------- LSTM body (512 threads, one block per n) ----------------
__device__ __forceinline__ void lstm_body(
    const int* __restrict__ q, const float* __restrict__ embW,
    const float* __restrict__ Wih, const float* __restrict__ Whh,
    const float* __restrict__ bih, const float* __restrict__ bhh,
    float* __restrict__ qf, int n)
{
    const int tid = threadIdx.x;
    __shared__ float xs[32], hs[RNN], cs[RNN], zg[512];
    float wih[32], whh[RNN];
#pragma unroll
    for (int j = 0; j < 32; j++) wih[j] = Wih[tid * 32 + j];
#pragma unroll
    for (int j = 0; j < RNN; j++) whh[j] = Whh[tid * RNN + j];
    const float bias = bih[tid] + bhh[tid];
    if (tid < RNN) { hs[tid] = 0.f; cs[tid] = 0.f; }
    __syncthreads();
    for (int t = 0; t < TT; t++) {
        if (tid < 32) xs[tid] = embW[q[n * TT + t] * 32 + tid];
        __syncthreads();
        float acc = bias;
#pragma unroll
        for (int j = 0; j < 32; j++) acc += wih[j] * xs[j];
#pragma unroll
        for (int j = 0; j < RNN; j++) acc += whh[j] * hs[j];
        zg[tid] = acc;
        __syncthreads();
        if (tid < RNN) {
            float ig = 1.f / (1.f + expf(-zg[tid]));
            float fg = 1.f / (1.f + expf(-zg[RNN + tid]));
            float gg = tanhf(zg[2 * RNN + tid]);
            float og = 1.f / (1.f + expf(-zg[3 * RNN + tid]));
            float cn = fg * cs[tid] + ig * gg;
            cs[tid] = cn;
            hs[tid] = og * tanhf(cn);
        }
        __syncthreads();
    }
    if (tid < RNN) qf[n * RNN + tid] = hs[tid];
}

// ---------------- tiled conv 3x3 s2 p1 body ----------------
template<int CIN, int TILE, bool BNIN, int BS>
__device__ __forceinline__ void conv_body(
    const float* __restrict__ in, const float* __restrict__ Wg,
    const float* __restrict__ bias,
    const float* __restrict__ pstats, const float* __restrict__ pg,
    const float* __restrict__ pb, float pinvM,
    float* __restrict__ out, float* __restrict__ stats,
    int HIN, int WIN, int HO, int WO, int tilesX, int bx)
{
    constexpr int NPIX = TILE * TILE;
    constexpr int CPG  = BS / NPIX;       // co-groups
    constexpr int COPT = 24 / CPG;        // channels per thread
    constexpr int WPB  = BS / 64;         // waves per block
    constexpr int WPC  = NPIX / 64;       // waves per co-group
    constexpr int S  = 2 * TILE + 1;
    constexpr int SP = S + 1;
    __shared__ float in_t[CIN][S][SP];
    __shared__ float r1s[WPB][COPT], r2s[WPB][COPT];
    __shared__ float sc[CIN], sh[CIN];
    const int tid = threadIdx.x;
    const int tx = bx % tilesX;
    const int ty = (bx / tilesX) % tilesX;
    const int n  = bx / (tilesX * tilesX);

    if (BNIN) {
        if (tid < CIN) {
            float mu  = pstats[2 * tid] * pinvM;
            float var = pstats[2 * tid + 1] * pinvM - mu * mu;
            float rs  = rsqrtf(var + 1e-5f);
            sc[tid] = rs * pg[tid];
            sh[tid] = pb[tid] - mu * rs * pg[tid];
        }
        __syncthreads();
    }
    const int iy0 = ty * 2 * TILE - 1, ix0 = tx * 2 * TILE - 1;
    for (int idx = tid; idx < CIN * S * S; idx += BS) {
        int ci = idx / (S * S), r = idx % (S * S);
        int ry = r / S, rx = r % S;
        int gy = iy0 + ry, gx = ix0 + rx;
        float v = 0.f;
        if ((unsigned)gy < (unsigned)HIN && (unsigned)gx < (unsigned)WIN) {
            v = in[((size_t)(n * CIN + ci) * HIN + gy) * WIN + gx];
            if (BNIN) v = fmaxf(v * sc[ci] + sh[ci], 0.f);
        }
        in_t[ci][ry][rx] = v;
    }
    __syncthreads();

    const int p   = tid % NPIX;
    const int co0 = __builtin_amdgcn_readfirstlane((tid / NPIX) * COPT);
    const int ly  = (p / TILE) * 2, lx = (p % TILE) * 2;
    float acc[COPT];
#pragma unroll
    for (int c = 0; c < COPT; c++) acc[c] = bias[co0 + c];
    for (int ci = 0; ci < CIN; ci++) {
#pragma unroll
        for (int ky = 0; ky < 3; ky++) {
            const float* row = &in_t[ci][ly + ky][lx];
#pragma unroll
            for (int kx = 0; kx < 3; kx++) {
                float v = row[kx];
#pragma unroll
                for (int c = 0; c < COPT; c++)
                    acc[c] += v * Wg[(((co0 + c) * CIN + ci) * 3 + ky) * 3 + kx];
            }
        }
    }
    const int oy = ty * TILE + p / TILE, ox = tx * TILE + p % TILE;
#pragma unroll
    for (int c = 0; c < COPT; c++)
        out[((size_t)(n * 24 + co0 + c) * HO + oy) * WO + ox] = acc[c];

    const int lane = tid & 63, wv = tid >> 6;
#pragma unroll
    for (int c = 0; c < COPT; c++) {
        float s1 = acc[c], s2 = acc[c] * acc[c];
#pragma unroll
        for (int off = 1; off < 64; off <<= 1) {
            s1 += __shfl_xor(s1, off, 64);
            s2 += __shfl_xor(s2, off, 64);
        }
        if (lane == 0) { r1s[wv][c] = s1; r2s[wv][c] = s2; }
    }
    __syncthreads();
    if (tid < 24) {
        int cg = tid / COPT, slot = tid % COPT;
        float t1 = 0.f, t2 = 0.f;
#pragma unroll
        for (int u = 0; u < WPC; u++) { t1 += r1s[cg * WPC + u][slot]; t2 += r2s[cg * WPC + u][slot]; }
        atomicAdd(&stats[tid * 2],     t1);
        atomicAdd(&stats[tid * 2 + 1], t2);
    }
}

template<int CIN, int TILE, bool BNIN>
__global__ __launch_bounds__(256) void conv_tiled(
    const float* __restrict__ in, const float* __restrict__ Wg,
    const float* __restrict__ bias,
    const float* __restrict__ pstats, const float* __restrict__ pg,
    const float* __restrict__ pb, float pinvM,
    float* __restrict__ out, float* __restrict__ stats,
    int HIN, int WIN, int HO, int WO, int tilesX)
{
    conv_body<CIN, TILE, BNIN, 256>(in, Wg, bias, pstats, pg, pb, pinvM,
                                    out, stats, HIN, WIN, HO, WO, tilesX, blockIdx.x);
}

// ---------------- merged front: lstm (blocks 0-31) + conv0 (32-543) + cvt (544-639) ----------------
__global__ __launch_bounds__(512) void fused_front(
    const int* __restrict__ q, const float* __restrict__ embW,
    const float* __restrict__ Wih, const float* __restrict__ Whh,
    const float* __restrict__ bih, const float* __restrict__ bhh,
    float* __restrict__ qf,
    const float* __restrict__ images, const float* __restrict__ c0W,
    const float* __restrict__ c0b, float* __restrict__ conv0o,
    float* __restrict__ stats,
    const float* __restrict__ gsW, unsigned short* __restrict__ Wbf)
{
    const int bx = blockIdx.x;
    if (bx < 32) {
        lstm_body(q, embW, Wih, Whh, bih, bhh, qf, bx);
    } else if (bx < 544) {
        conv_body<3, 16, false, 512>(images, c0W, c0b, nullptr, nullptr, nullptr, 0.f,
                                     conv0o, stats, 128, 128, 64, 64, 4, bx - 32);
    } else {
        int i = ((bx - 544) << 9) + threadIdx.x;
#pragma unroll
        for (int u = 0; u < 4; u++) {
            Wbf[i] = f2bf(gsW[i]);
            i += 96 * 512;
        }
    }
}

// ---------------- A,B,QT projections: 4 blocks per n ----------------
__global__ __launch_bounds__(256) void abqt_kernel(
    const float* __restrict__ feat,  // (32,24,8,8) raw conv3
    const float* __restrict__ stats, const float* __restrict__ g,
    const float* __restrict__ b, float invM,
    const float* __restrict__ qf,    // (32,128)
    const float* __restrict__ g0W,   // (256,180)
    const float* __restrict__ g0b,
    float* __restrict__ A, float* __restrict__ Bm, float* __restrict__ QT)
{
    const int n = blockIdx.x >> 2, iq = blockIdx.x & 3, k = threadIdx.x;
    __shared__ float obj[16][28];
    __shared__ float qs[RNN];
    __shared__ float sc[24], sh[24];
    if (k < 24) {
        float mu  = stats[2 * k] * invM;
        float var = stats[2 * k + 1] * invM - mu * mu;
        float rs  = rsqrtf(var + 1e-5f);
        sc[k] = rs * g[k];
        sh[k] = b[k] - mu * rs * g[k];
    }
    if (iq == 0 && k >= 128) qs[k - 128] = qf[n * RNN + (k - 128)];
    __syncthreads();
    for (int idx = k; idx < 24 * 16; idx += 256) {
        int c = idx >> 4, il = idx & 15;
        int i = (iq << 4) + il;
        float v = feat[(n * CDIM + c) * 64 + i];
        obj[il][c] = fmaxf(v * sc[c] + sh[c], 0.f);
    }
    if (k < 16) {
        int i = (iq << 4) + k;
        obj[k][24] = (float)(i & 7)  * (1.f / 7.f);   // xc
        obj[k][25] = (float)(i >> 3) * (1.f / 7.f);   // yc
        obj[k][26] = 0.f; obj[k][27] = 0.f;
    }
    __syncthreads();
    const float* wr = g0W + k * GIN;
    float wA[26], wB[26];
#pragma unroll
    for (int c = 0; c < 26; c++) { wA[c] = wr[c]; wB[c] = wr[26 + c]; }
    if (iq == 0) {
        float qv = g0b[k];
#pragma unroll
        for (int d = 0; d < RNN; d++) qv += wr[52 + d] * qs[d];
        QT[(n << 8) + k] = qv;
    }
    for (int il = 0; il < 16; il++) {
        const f32x4* op = (const f32x4*)obj[il];
        f32x4 r0 = op[0], r1 = op[1], r2 = op[2], r3 = op[3],
              r4 = op[4], r5 = op[5], r6 = op[6];
        float a = 0.f, bb = 0.f;
#pragma unroll
        for (int p = 0; p < 4; p++) {
            a += wA[p] * r0[p] + wA[4 + p] * r1[p] + wA[8 + p] * r2[p]
               + wA[12 + p] * r3[p] + wA[16 + p] * r4[p] + wA[20 + p] * r5[p];
            bb += wB[p] * r0[p] + wB[4 + p] * r1[p] + wB[8 + p] * r2[p]
                + wB[12 + p] * r3[p] + wB[16 + p] * r4[p] + wB[20 + p] * r5[p];
        }
        a += wA[24] * r6[0] + wA[25] * r6[1];
        bb += wB[24] * r6[0] + wB[25] * r6[1];
        int i = (iq << 4) + il;
        A [(((n << 6) + i) << 8) + k] = a;
        Bm[(((n << 6) + i) << 8) + k] = bb;
    }
}

// ---------------- fused 3x(256->256) g-MLP + pair sum, bf16 MFMA ----------------
// 512 threads = 8 waves (2 row-halves x 4 col-quarters); 128 pair-rows/block;
// X in LDS (bf16, XOR-swizzled); W direct global->reg; 6 barriers total
__global__ __launch_bounds__(512, 4) void gs_fused(
    const float* __restrict__ A, const float* __restrict__ Bm, const float* __restrict__ QT,
    const unsigned short* __restrict__ Wb,   // (3,256,256) bf16
    const float* __restrict__ gsb,           // (3,256)
    float* __restrict__ partial)             // (2048,256)
{
    __shared__ __align__(16) unsigned short Xs[128 * 256];  // 64 KB
    __shared__ float AQ[2][256];
    __shared__ float biasv[3][256];
    const int bb = blockIdx.x, n = bb >> 5, ip = bb & 31, tid = threadIdx.x;
    const int lane = tid & 63, w = tid >> 6, l15 = lane & 15, lh = lane >> 4;
    const int rh = w >> 2, cq = w & 3;

    if (tid < 256) {
        float qt = QT[(n << 8) + tid];
        AQ[0][tid] = A[(((n << 6) + ip * 2)     << 8) + tid] + qt;
        AQ[1][tid] = A[(((n << 6) + ip * 2 + 1) << 8) + tid] + qt;
        biasv[0][tid] = gsb[tid];
        biasv[1][tid] = gsb[256 + tid];
        biasv[2][tid] = gsb[512 + tid];
    }
    __syncthreads();

    // build h0 = relu(A_i + B_j + QT) into Xs; 128 rows x 32 col-groups
#pragma unroll
    for (int it = 0; it < 8; it++) {
        int task = tid + (it << 9);
        int r = task >> 5, g = task & 31;
        int isub = r >> 6, j = r & 63;
        const f32x4* bp = (const f32x4*)(Bm + (((n << 6) + j) << 8) + (g << 3));
        f32x4 b0 = bp[0], b1 = bp[1];
        u16x8 pk;
        int c0 = g << 3;
#pragma unroll
        for (int p = 0; p < 4; p++) {
            pk[p]     = f2bf(fmaxf(b0[p] + AQ[isub][c0 + p], 0.f));
            pk[p + 4] = f2bf(fmaxf(b1[p] + AQ[isub][c0 + 4 + p], 0.f));
        }
        *(u16x8*)((char*)Xs + r * 512 + ((g ^ (r & 7)) << 4)) = pk;
    }

    f32x4 acc[4][4];                 // [col-tile][row-slab]
    const f32x4 zero4 = {0.f, 0.f, 0.f, 0.f};
    for (int layer = 0; layer < 3; layer++) {
#pragma unroll
        for (int tc = 0; tc < 4; tc++)
#pragma unroll
            for (int sl = 0; sl < 4; sl++) acc[tc][sl] = zero4;
        // per-lane W base: row ko = cq*64 + tc*16 + l15, K offset lh*8 (+kb*32)
        const unsigned short* wbase = Wb + (layer << 16)
                                    + (((cq << 6) + l15) << 8) + (lh << 3);
        __syncthreads();   // Xs ready (build or previous writeback)
#pragma unroll
        for (int kb = 0; kb < 8; kb++) {
            bf16x8 wa[4];
#pragma unroll
            for (int tc = 0; tc < 4; tc++)
                wa[tc] = *(const bf16x8*)(wbase + (tc << 12) + (kb << 5));
            bf16x8 xf[4];
#pragma unroll
            for (int sl = 0; sl < 4; sl++) {
                int ar = (rh << 6) + (sl << 4) + l15;
                int au = ((kb << 2) + lh) ^ (ar & 7);
                xf[sl] = *(const bf16x8*)((const char*)Xs + ar * 512 + (au << 4));
            }
#pragma unroll
            for (int tc = 0; tc < 4; tc++)
#pragma unroll
                for (int sl = 0; sl < 4; sl++)
                    acc[tc][sl] = __builtin_amdgcn_mfma_f32_16x16x32_bf16(
                        wa[tc], xf[sl], acc[tc][sl], 0, 0, 0);
        }
        if (layer < 2) {
            __syncthreads();  // all waves done reading Xs before overwrite
#pragma unroll
            for (int tc = 0; tc < 4; tc++) {
                int c0 = (cq << 6) + (tc << 4) + (lh << 2);
                float b0 = biasv[layer][c0],     b1 = biasv[layer][c0 + 1];
                float b2 = biasv[layer][c0 + 2], b3 = biasv[layer][c0 + 3];
#pragma unroll
                for (int sl = 0; sl < 4; sl++) {
                    int row = (rh << 6) + (sl << 4) + l15;
                    s16x4 pk;
                    pk[0] = (short)f2bf(fmaxf(acc[tc][sl][0] + b0, 0.f));
                    pk[1] = (short)f2bf(fmaxf(acc[tc][sl][1] + b1, 0.f));
                    pk[2] = (short)f2bf(fmaxf(acc[tc][sl][2] + b2, 0.f));
                    pk[3] = (short)f2bf(fmaxf(acc[tc][sl][3] + b3, 0.f));
                    *(s16x4*)((char*)Xs + row * 512 + (((c0 >> 3) ^ (row & 7)) << 4)
                              + ((c0 & 7) << 1)) = pk;
                }
            }
        } else {
            // final: relu + sum over this wave's 64 rows -> partial[bb*2+rh][col]
#pragma unroll
            for (int tc = 0; tc < 4; tc++) {
                int c0 = (cq << 6) + (tc << 4) + (lh << 2);
                f32x4 cs;
#pragma unroll
                for (int p = 0; p < 4; p++) {
                    float bv = biasv[2][c0 + p];
                    float s = 0.f;
#pragma unroll
                    for (int sl = 0; sl < 4; sl++) s += fmaxf(acc[tc][sl][p] + bv, 0.f);
                    s += __shfl_xor(s, 1, 64);
                    s += __shfl_xor(s, 2, 64);
                    s += __shfl_xor(s, 4, 64);
                    s += __shfl_xor(s, 8, 64);
                    cs[p] = s;
                }
                if (l15 == 0)
                    *(f32x4*)(partial + (size_t)(bb * 2 + rh) * 256 + c0) = cs;
            }
        }
    }
}

// ---------------- f-MLP ----------------
__global__ __launch_bounds__(256) void f_mlp(
    const float* __restrict__ partial,
    const float* __restrict__ f0W, const float* __restrict__ f0b,
    const float* __restrict__ f1W, const float* __restrict__ f1b,
    const float* __restrict__ f2W, const float* __restrict__ f2b,
    float* __restrict__ out)
{
    const int n = blockIdx.x, k = threadIdx.x;
    __shared__ float fin[256], h1[256], h2[256];
    float s = 0.f;
    for (int b = 0; b < 64; b++) s += partial[(size_t)(n * 64 + b) * 256 + k];
    fin[k] = s;
    __syncthreads();
    const float* wr = f0W + k * 256;
    float a = f0b[k];
    for (int c = 0; c < 256; c++) a += wr[c] * fin[c];
    h1[k] = fmaxf(a, 0.f);
    __syncthreads();
    wr = f1W + k * 256;
    a = f1b[k];
    for (int c = 0; c < 256; c++) a += wr[c] * h1[c];
    h2[k] = fmaxf(a, 0.f);
    __syncthreads();
    if (k < 32) {
        wr = f2W + k * 256;
        a = f2b[k];
        for (int c = 0; c < 256; c++) a += wr[c] * h2[c];
        out[n * 32 + k] = a;
    }
}

extern "C" void kernel_launch(void* const* d_in, const int* in_sizes, int n_in,
                              void* d_out, int out_size, void* d_ws, size_t ws_size,
                              hipStream_t stream)
{
    const int*   questions = (const int*)  d_in[0];
    const float* images = (const float*)d_in[1];
    const float* embW   = (const float*)d_in[2];
    const float* Wih    = (const float*)d_in[3];
    const float* Whh    = (const float*)d_in[4];
    const float* bih    = (const float*)d_in[5];
    const float* bhh    = (const float*)d_in[6];
    const float* c0W    = (const float*)d_in[7];
    const float* c0b    = (const float*)d_in[8];
    const float* bn0g   = (const float*)d_in[9];
    const float* bn0b   = (const float*)d_in[10];
    const float* csW    = (const float*)d_in[11];
    const float* csb    = (const float*)d_in[12];
    const float* bnsg   = (const float*)d_in[13];
    const float* bnsb   = (const float*)d_in[14];
    const float* g0W    = (const float*)d_in[15];
    const float* g0b    = (const float*)d_in[16];
    const float* gsW    = (const float*)d_in[17];
    const float* gsb    = (const float*)d_in[18];
    const float* f0W    = (const float*)d_in[19];
    const float* f0b    = (const float*)d_in[20];
    const float* f1W    = (const float*)d_in[21];
    const float* f1b    = (const float*)d_in[22];
    const float* f2W    = (const float*)d_in[23];
    const float* f2b    = (const float*)d_in[24];

    float* ws  = (float*)d_ws;
    float* out = (float*)d_out;

    // workspace layout (floats)
    float* conv0o = ws;                 // 3,145,728  (32,24,64,64)
    float* conv1o = ws + 3145728;       //   786,432  (32,24,32,32)
    float* conv2o = ws + 3932160;       //   196,608  (32,24,16,16)
    float* conv3o = ws + 4128768;       //    49,152  (32,24,8,8)
    float* stats  = ws + 4177920;       //       192
    float* qf     = ws + 4178112;       //     4,096  (32,128)
    unsigned short* Wbf = (unsigned short*)(ws + 4182208);  // 196,608 bf16 (98,304 f)
    // overlay into conv0o region (dead after conv1 consumes it):
    float* Abuf   = ws;                 //   524,288  (32,64,256)
    float* Bbuf   = ws + 524288;        //   524,288
    float* QTb    = ws + 1048576;       //     8,192  (32,256)
    float* part   = ws + 1155072;       //   524,288  (2048,256)

    hipMemsetAsync(stats, 0, 192 * sizeof(float), stream);

    // lstm (32 blocks, launched first) + conv0 (512) + gsW->bf16 cvt (96)
    fused_front<<<640, 512, 0, stream>>>(questions, embW, Wih, Whh, bih, bhh, qf,
                                         images, c0W, c0b, conv0o, stats, gsW, Wbf);
    // conv1: BN0 applied on load; out (32,24,32,32); 8x8 tiles, 4x4 grid
    conv_tiled<24, 8, true><<<512, 256, 0, stream>>>(
        conv0o, csW, csb, stats, bn0g, bn0b, 1.f / 131072.f,
        conv1o, stats + 48, 64, 64, 32, 32, 4);
    // conv2: out (32,24,16,16); 2x2 grid
    conv_tiled<24, 8, true><<<128, 256, 0, stream>>>(
        conv1o, csW + 5184, csb + 24, stats + 48, bnsg, bnsb, 1.f / 32768.f,
        conv2o, stats + 96, 32, 32, 16, 16, 2);
    // conv3: out (32,24,8,8); 1x1 grid
    conv_tiled<24, 8, true><<<32, 256, 0, stream>>>(
        conv2o, csW + 10368, csb + 48, stats + 96, bnsg + 24, bnsb + 24, 1.f / 8192.f,
        conv3o, stats + 144, 16, 16, 8, 8, 1);

    abqt_kernel<<<128, 256, 0, stream>>>(conv3o, stats + 144, bnsg + 48, bnsb + 48,
                                         1.f / 2048.f, qf, g0W, g0b, Abuf, Bbuf, QTb);
    gs_fused<<<1024, 512, 0, stream>>>(Abuf, Bbuf, QTb, Wbf, gsb, part);
    f_mlp<<<32, 256, 0, stream>>>(part, f0W, f0b, f1W, f1b, f2W, f2b, out);
}